// Round 4
// baseline (2705.527 us; speedup 1.0000x reference)
//
#include <hip/hip_runtime.h>
#include <math.h>

#define KK 10
#define NN 96
#define TT 40
#define HID 48

#define HZf 10.0f
#define R0f 0.5f
#define R1f 4.0f
#define RSTEPf ((4.0f - 0.5f) / 6.0f)
#define TWO_PIf 6.2831853071795864769f
#define TSTEPf (6.2831853071795864769f / 6.0f)

typedef short s16x8 __attribute__((ext_vector_type(8)));
typedef float f32x4 __attribute__((ext_vector_type(4)));
typedef unsigned short u16;

__device__ __forceinline__ u16 f2bf(float f) {
    union { float f; unsigned u; } v; v.f = f;
    unsigned r = v.u + 0x7fffu + ((v.u >> 16) & 1u);
    return (u16)(r >> 16);
}
__device__ __forceinline__ float bf2f(u16 h) {
    union { unsigned u; float f; } v; v.u = ((unsigned)h) << 16;
    return v.f;
}

// ---------------- conv1 ----------------
__global__ void conv1_k(const float* __restrict__ img, const float* __restrict__ w,
                        const float* __restrict__ b, float* __restrict__ out) {
    int idx = blockIdx.x * blockDim.x + threadIdx.x;
    if (idx >= 16 * 80 * 80) return;
    int x = idx % 80, y = (idx / 80) % 80, o = idx / 6400;
    float acc = b[o];
    for (int c = 0; c < 4; c++)
        for (int ky = 0; ky < 5; ky++) {
            int iy = y * 2 + ky - 2;
            if (iy < 0 || iy >= 160) continue;
            for (int kx = 0; kx < 5; kx++) {
                int ix = x * 2 + kx - 2;
                if (ix < 0 || ix >= 160) continue;
                acc += img[(c * 160 + iy) * 160 + ix] * w[((o * 4 + c) * 5 + ky) * 5 + kx];
            }
        }
    out[idx] = fmaxf(acc, 0.0f);
}

// ---------------- conv2 ----------------
__global__ void conv2_k(const float* __restrict__ in, const float* __restrict__ w,
                        const float* __restrict__ b, float* __restrict__ out) {
    int idx = blockIdx.x * blockDim.x + threadIdx.x;
    if (idx >= 32 * 80 * 80) return;
    int x = idx % 80, y = (idx / 80) % 80, o = idx / 6400;
    float acc = b[o];
    for (int c = 0; c < 16; c++)
        for (int ky = 0; ky < 5; ky++) {
            int iy = y + ky - 2;
            if (iy < 0 || iy >= 80) continue;
            for (int kx = 0; kx < 5; kx++) {
                int ix = x + kx - 2;
                if (ix < 0 || ix >= 80) continue;
                acc += in[(c * 80 + iy) * 80 + ix] * w[((o * 16 + c) * 5 + ky) * 5 + kx];
            }
        }
    out[idx] = fmaxf(acc, 0.0f);
}

// ---------------- weight prep: bf16, MFMA-B layout Bt[n][k] ----------------
// wscf_t[36][48][64]: Bt[n=o][k=d] = scf[o*1728 + b*48 + d], d>=48 -> 0
// wrz_g[96][160]: gates r,z: k<96 wih[g][k]; k<144 whh[g][k-96]; else 0
// win_g[48][96]: gate in: wih[96+n][k]
// whn_g[48][64]: gate hn: whh[96+n][k], k>=48 -> 0
// bias5[5][48]: bR, bZ, bIN, bHN, scfb
__global__ void prep_w2(const float* __restrict__ scf, const float* __restrict__ wih,
                        const float* __restrict__ whh, const float* __restrict__ bih,
                        const float* __restrict__ bhh, const float* __restrict__ scfb,
                        u16* __restrict__ wscf_t, u16* __restrict__ wrz_g,
                        u16* __restrict__ win_g, u16* __restrict__ whn_g,
                        float* __restrict__ bias5) {
    int idx = blockIdx.x * blockDim.x + threadIdx.x;
    if (idx < 110592) {
        int kk = idx & 63, n = (idx >> 6) % 48, b = idx / 3072;
        float v = (kk < 48) ? scf[n * 1728 + b * 48 + kk] : 0.f;
        wscf_t[idx] = f2bf(v);
    } else if (idx < 110592 + 15360) {
        int j = idx - 110592;
        int kk = j % 160, g = j / 160;
        float v = (kk < 96) ? wih[g * 96 + kk] : (kk < 144 ? whh[g * 48 + kk - 96] : 0.f);
        wrz_g[j] = f2bf(v);
    } else if (idx < 110592 + 15360 + 4608) {
        int j = idx - 110592 - 15360;
        int kk = j % 96, n = j / 96;
        win_g[j] = f2bf(wih[(96 + n) * 96 + kk]);
    } else if (idx < 110592 + 15360 + 4608 + 3072) {
        int j = idx - 110592 - 15360 - 4608;
        int kk = j & 63, n = j >> 6;
        whn_g[j] = f2bf(kk < 48 ? whh[(96 + n) * 48 + kk] : 0.f);
    } else if (idx < 110592 + 15360 + 4608 + 3072 + 240) {
        int j = idx - (110592 + 15360 + 4608 + 3072);
        int od = j % 48, q = j / 48;
        float v;
        if (q == 0) v = bih[od] + bhh[od];
        else if (q == 1) v = bih[48 + od] + bhh[48 + od];
        else if (q == 2) v = bih[96 + od];
        else if (q == 3) v = bhh[96 + od];
        else v = scfb[od];
        bias5[j] = v;
    }
}

// ---------------- lhalf (bf16 out) ----------------
__global__ void lhalf_k(const float* __restrict__ yp, const float* __restrict__ cur,
                        const float* __restrict__ fmap, const float* __restrict__ vw,
                        const float* __restrict__ vb, u16* __restrict__ lhalf_bf) {
    int item = blockIdx.x;  // t*K*N + k*N + n
    int n = item % NN, k = (item / NN) % KK, t = item / (KK * NN);
    int lane = threadIdx.x;
    float lx = yp[((k * TT + t) * NN + n) * 2 + 0];
    float ly = yp[((k * TT + t) * NN + n) * 2 + 1];
    float px, py;
    if (t == 0) { px = cur[n * 2]; py = cur[n * 2 + 1]; }
    else { px = yp[((k * TT + t - 1) * NN + n) * 2]; py = yp[((k * TT + t - 1) * NN + n) * 2 + 1]; }
    float vx = (lx - px) * HZf, vy = (ly - py) * HZf;
    int ui = 40 - (int)ly;
    int vi = 40 - (int)lx;
    ui = min(max(ui, 0), 79);
    vi = min(max(vi, 0), 79);
    int row = k * NN + n;
    u16* dst = lhalf_bf + ((size_t)t * KK * NN + row) * 48;
    if (lane < 32) {
        dst[lane] = f2bf(fmap[(lane * 80 + ui) * 80 + vi]);
    } else if (lane < 48) {
        int f = lane - 32;
        float a = vb[f] + vx * vw[f * 2 + 0] + vy * vw[f * 2 + 1];
        dst[lane] = f2bf(fmaxf(a, 0.0f));
    }
}

// ---------------- bins ----------------
__global__ __launch_bounds__(256) void bins2_k(const float* __restrict__ yp,
                                               signed char* __restrict__ win,
                                               unsigned char* __restrict__ cnt) {
    int tk = blockIdx.x;  // t*10 + k
    int k = tk % KK, t = tk / KK;
    int tid = threadIdx.x;
    __shared__ float xs[96], ys[96];
    __shared__ int win_s[96 * 36];
    __shared__ int cnt_s[96 * 36];
    if (tid < 96) {
        xs[tid] = yp[((k * TT + t) * NN + tid) * 2 + 0];
        ys[tid] = yp[((k * TT + t) * NN + tid) * 2 + 1];
    }
    for (int i = tid; i < 96 * 36; i += 256) { win_s[i] = -1; cnt_s[i] = 0; }
    __syncthreads();
    for (int p = tid; p < 96 * 96; p += 256) {
        int i = p / 96, j = p % 96;
        if (i == j) continue;
        float dx = xs[j] - xs[i], dy = ys[j] - ys[i];
        float dist = sqrtf(dx * dx + dy * dy);
        if (dist < R0f || dist > R1f) continue;
        float dsafe = fmaxf(dist, 1e-10f);
        float cost = fminf(fmaxf(dx / dsafe, -1.0f), 1.0f);
        float ac = acosf(cost);
        float theta = (dy < 0.0f) ? (TWO_PIf - ac) : ac;
        int ub = (int)((dist - R0f) / RSTEPf); ub = min(max(ub, 0), 5);
        int vb = (int)(theta / TSTEPf);        vb = min(max(vb, 0), 5);
        int b = ub * 6 + vb;
        atomicAdd(&cnt_s[i * 36 + b], 1);
        atomicMax(&win_s[i * 36 + b], j);
    }
    __syncthreads();
    size_t base = (size_t)tk * 96 * 36;
    for (int i = tid; i < 96 * 36; i += 256) {
        win[base + i] = (signed char)win_s[i];
        cnt[base + i] = (unsigned char)cnt_s[i];
    }
}

// ---------------- recurrent block (MFMA) ----------------
// LDS layout (bytes):
//   Wrz  [96][168] bf16      @ 0       (32256)
//   Z    [96][168] bf16      @ 32256   (cols: 0..47 lhalf, 48..95 rhalf, 96..143 h, 144..159 zero)
//   Hs   [96][72]  bf16      @ 64512   (cols 0..47 = chain h, 48..63 zero)
//   U    [96][6][48] bf16    @ 78336   (aliased by G [96][200] bf16 in phase B/C)
//   winl [96][36] i8         @ 133632
//   cntl [96][36] u8         @ 137088
//   scl  [96] f32            @ 140544
#define SMEM_BYTES 140928

template <bool CHAIN>
__device__ __forceinline__ void recur_block(
    int rowbase, const float* __restrict__ hx, float* __restrict__ h0hist,
    const u16* __restrict__ lhalf_bf, const signed char* __restrict__ win,
    const unsigned char* __restrict__ cnt, const u16* __restrict__ wscf_t,
    const u16* __restrict__ wrz_g, const u16* __restrict__ win_g,
    const u16* __restrict__ whn_g, const float* __restrict__ bias5,
    const float* __restrict__ scw, float* __restrict__ score_acc,
    float* __restrict__ hfin) {
    extern __shared__ char smem[];
    u16* Wrz = (u16*)(smem);
    u16* Z = (u16*)(smem + 32256);
    u16* Hs = (u16*)(smem + 64512);
    u16* U = (u16*)(smem + 78336);
    u16* G = (u16*)(smem + 78336);
    signed char* winl = (signed char*)(smem + 133632);
    unsigned char* cntl = (unsigned char*)(smem + 137088);
    float* scl = (float*)(smem + 140544);

    const int tid = threadIdx.x;
    const int wv = tid >> 6;
    const int lane = tid & 63;
    const int l15 = lane & 15, l16 = lane >> 4;

    // ---- init ----
    for (int i = tid; i < 7680; i += 1024) {
        int r = (2 * i) / 160, c = (2 * i) % 160;
        *(unsigned*)((char*)Wrz + (size_t)(r * 168 + c) * 2) = *(const unsigned*)(wrz_g + 2 * i);
    }
    for (int i = tid; i < 768; i += 1024) {  // Z zero cols 144..159
        int r = i >> 3, c = 144 + ((i & 7) << 1);
        *(unsigned*)((char*)Z + (size_t)(r * 168 + c) * 2) = 0;
    }
    for (int i = tid; i < 1152; i += 1024) {  // Hs zero cols 48..71
        int r = i / 12, c = 48 + (i % 12) * 2;
        *(unsigned*)((char*)Hs + (size_t)(r * 72 + c) * 2) = 0;
    }
    if (tid < 96) scl[tid] = 0.0f;

    float hreg[5], part[5], swr[5], bR[5], bZ[5], bIN[5], bHN[5], sFB[5];
#pragma unroll
    for (int i = 0; i < 5; ++i) {
        int idx = tid + (i << 10);
        if (idx < 4608) {
            int r = idx / 48, od = idx - r * 48;
            float h0 = hx[r * 48 + od];  // rowbase % 96 == 0
            hreg[i] = h0; part[i] = 0.f;
            swr[i] = scw[od];
            bR[i] = bias5[od]; bZ[i] = bias5[48 + od];
            bIN[i] = bias5[96 + od]; bHN[i] = bias5[144 + od];
            sFB[i] = bias5[192 + od];
            u16 hb = f2bf(h0);
            Z[r * 168 + 96 + od] = hb;
            Hs[r * 72 + od] = hb;
            if (CHAIN) h0hist[idx] = h0;
        } else {
            hreg[i] = 0.f; part[i] = 0.f; swr[i] = 0.f;
            bR[i] = bZ[i] = bIN[i] = bHN[i] = sFB[i] = 0.f;
        }
    }
    __syncthreads();

    for (int t = 0; t < TT; ++t) {
        // ---- S0: stage lhalf, win/cnt, (followers) Hsrc ----
        {
            const unsigned* src = (const unsigned*)(lhalf_bf + ((size_t)t * 960 + rowbase) * 48);
            for (int i = tid; i < 2304; i += 1024) {
                int r = (2 * i) / 48, c = (2 * i) % 48;
                *(unsigned*)((char*)Z + (size_t)(r * 168 + c) * 2) = src[i];
            }
            const unsigned* ws32 = (const unsigned*)(win + ((size_t)t * 960 + rowbase) * 36);
            const unsigned* cs32 = (const unsigned*)(cnt + ((size_t)t * 960 + rowbase) * 36);
            for (int i = tid; i < 864; i += 1024) {
                ((unsigned*)winl)[i] = ws32[i];
                ((unsigned*)cntl)[i] = cs32[i];
            }
        }
        if (!CHAIN) {
            const float* hsrc_g = h0hist + (size_t)t * 4608;
            for (int i = tid; i < 4608; i += 1024) {
                int r = i / 48, od = i - r * 48;
                Hs[r * 72 + od] = f2bf(hsrc_g[i]);
            }
        }
        __syncthreads();

        // ---- phase A: rhalf ----
        float rh[5];
#pragma unroll
        for (int i = 0; i < 5; ++i) rh[i] = 0.f;
        for (int batch = 0; batch < 6; ++batch) {
            // U[j][lb][o] = (Hs[j] @ W_b^T)[o]
            for (int task = wv; task < 18; task += 16) {
                int lb = task / 3, nt = task - lb * 3;
                int b = batch * 6 + lb;
                const u16* bp = wscf_t + (size_t)(b * 48 + nt * 16 + l15) * 64 + l16 * 8;
                s16x8 bf0 = *(const s16x8*)(bp);
                s16x8 bf1 = *(const s16x8*)(bp + 32);
#pragma unroll
                for (int mt = 0; mt < 6; ++mt) {
                    int arow = mt * 16 + l15;
                    s16x8 a0 = *(s16x8*)((char*)Hs + (size_t)(arow * 72 + l16 * 8) * 2);
                    s16x8 a1 = *(s16x8*)((char*)Hs + (size_t)(arow * 72 + 32 + l16 * 8) * 2);
                    f32x4 acc = {0.f, 0.f, 0.f, 0.f};
                    acc = __builtin_amdgcn_mfma_f32_16x16x32_bf16(a0, bf0, acc, 0, 0, 0);
                    acc = __builtin_amdgcn_mfma_f32_16x16x32_bf16(a1, bf1, acc, 0, 0, 0);
                    int drow = mt * 16 + l16 * 4;
                    int dcol = lb * 48 + nt * 16 + l15;
#pragma unroll
                    for (int rr = 0; rr < 4; ++rr)
                        U[(drow + rr) * 288 + dcol] = f2bf(acc[rr]);
                }
            }
            __syncthreads();
            // gather
#pragma unroll
            for (int i = 0; i < 5; ++i) {
                int idx = tid + (i << 10);
                if (idx < 4608) {
                    int r = idx / 48, od = idx - r * 48;
#pragma unroll
                    for (int lb = 0; lb < 6; ++lb) {
                        int b = batch * 6 + lb;
                        int w = winl[r * 36 + b];
                        if (w >= 0) {
                            float c = (float)cntl[r * 36 + b];
                            rh[i] += bf2f(U[w * 288 + lb * 48 + od]) / c;
                        }
                    }
                }
            }
            __syncthreads();
        }
#pragma unroll
        for (int i = 0; i < 5; ++i) {
            int idx = tid + (i << 10);
            if (idx < 4608) {
                int r = idx / 48, od = idx - r * 48;
                Z[r * 168 + 48 + od] = f2bf(fmaxf(rh[i] + sFB[i], 0.f));
            }
        }
        __syncthreads();

        // ---- phase B: gates ----
        for (int task = wv; task < 72; task += 16) {
            f32x4 acc = {0.f, 0.f, 0.f, 0.f};
            int mt, colbase;
            if (task < 36) {
                mt = task / 6; int nt = task % 6;
#pragma unroll
                for (int kt = 0; kt < 5; ++kt) {
                    s16x8 a = *(s16x8*)((char*)Z + (size_t)((mt * 16 + l15) * 168 + kt * 32 + l16 * 8) * 2);
                    s16x8 b = *(s16x8*)((char*)Wrz + (size_t)((nt * 16 + l15) * 168 + kt * 32 + l16 * 8) * 2);
                    acc = __builtin_amdgcn_mfma_f32_16x16x32_bf16(a, b, acc, 0, 0, 0);
                }
                colbase = nt * 16;
            } else if (task < 54) {
                int tt2 = task - 36; mt = tt2 / 3; int nt = tt2 % 3;
                const u16* bg = win_g + (size_t)(nt * 16 + l15) * 96 + l16 * 8;
#pragma unroll
                for (int kt = 0; kt < 3; ++kt) {
                    s16x8 a = *(s16x8*)((char*)Z + (size_t)((mt * 16 + l15) * 168 + kt * 32 + l16 * 8) * 2);
                    s16x8 b = *(const s16x8*)(bg + kt * 32);
                    acc = __builtin_amdgcn_mfma_f32_16x16x32_bf16(a, b, acc, 0, 0, 0);
                }
                colbase = 96 + nt * 16;
            } else {
                int tt2 = task - 54; mt = tt2 / 3; int nt = tt2 % 3;
                const u16* bg = whn_g + (size_t)(nt * 16 + l15) * 64 + l16 * 8;
#pragma unroll
                for (int kt = 0; kt < 2; ++kt) {
                    s16x8 a = *(s16x8*)((char*)Z + (size_t)((mt * 16 + l15) * 168 + 96 + kt * 32 + l16 * 8) * 2);
                    s16x8 b = *(const s16x8*)(bg + kt * 32);
                    acc = __builtin_amdgcn_mfma_f32_16x16x32_bf16(a, b, acc, 0, 0, 0);
                }
                colbase = 144 + nt * 16;
            }
            int drow = mt * 16 + l16 * 4;
#pragma unroll
            for (int rr = 0; rr < 4; ++rr)
                G[(drow + rr) * 200 + colbase + l15] = f2bf(acc[rr]);
        }
        __syncthreads();

        // ---- phase C: elementwise GRU ----
#pragma unroll
        for (int i = 0; i < 5; ++i) {
            int idx = tid + (i << 10);
            if (idx < 4608) {
                int r = idx / 48, od = idx - r * 48;
                const u16* g = G + r * 200;
                float gr = bf2f(g[od]) + bR[i];
                float gz = bf2f(g[48 + od]) + bZ[i];
                float gi = bf2f(g[96 + od]) + bIN[i];
                float gh = bf2f(g[144 + od]) + bHN[i];
                float rr_ = 1.f / (1.f + __expf(-gr));
                float zz = 1.f / (1.f + __expf(-gz));
                float ng = tanhf(gi + rr_ * gh);
                float hn = (1.f - zz) * ng + zz * hreg[i];
                hreg[i] = hn;
                part[i] += hn * swr[i];
                u16 hb = f2bf(hn);
                Z[r * 168 + 96 + od] = hb;
                if (CHAIN) {
                    Hs[r * 72 + od] = hb;
                    h0hist[(size_t)(t + 1) * 4608 + idx] = hn;
                }
                if (t == TT - 1) hfin[(size_t)(rowbase + r) * 48 + od] = hn;
            }
        }
        __syncthreads();
    }

    // ---- score reduce ----
#pragma unroll
    for (int i = 0; i < 5; ++i) {
        int idx = tid + (i << 10);
        if (idx < 4608) atomicAdd(&scl[idx / 48], part[i]);
    }
    __syncthreads();
    if (tid < 96) score_acc[rowbase + tid] = scl[tid];
}

__global__ __launch_bounds__(1024) void chain_k(
    const float* hx, float* h0hist, const u16* lhalf_bf, const signed char* win,
    const unsigned char* cnt, const u16* wscf_t, const u16* wrz_g, const u16* win_g,
    const u16* whn_g, const float* bias5, const float* scw, float* score_acc, float* hfin) {
    recur_block<true>(0, hx, h0hist, lhalf_bf, win, cnt, wscf_t, wrz_g, win_g, whn_g,
                      bias5, scw, score_acc, hfin);
}

__global__ __launch_bounds__(1024) void foll_k(
    const float* hx, float* h0hist, const u16* lhalf_bf, const signed char* win,
    const unsigned char* cnt, const u16* wscf_t, const u16* wrz_g, const u16* win_g,
    const u16* whn_g, const float* bias5, const float* scw, float* score_acc, float* hfin) {
    recur_block<false>((1 + blockIdx.x) * 96, hx, h0hist, lhalf_bf, win, cnt, wscf_t,
                       wrz_g, win_g, whn_g, bias5, scw, score_acc, hfin);
}

// ---------------- epilogue ----------------
__global__ void final_k(const float* __restrict__ hlast, const float* __restrict__ score_acc,
                        const float* __restrict__ dyw, const float* __restrict__ dyb,
                        const float* __restrict__ scoreb, float* __restrict__ out) {
    int row = blockIdx.x, lane = threadIdx.x;
    int n = row % 96, k = row / 96;
    __shared__ float sh_h[48];
    if (lane < 48) sh_h[lane] = hlast[row * 48 + lane];
    __syncthreads();
    if (lane < 80) {
        float a = dyb[lane];
#pragma unroll 8
        for (int d = 0; d < 48; d++) a += sh_h[d] * dyw[lane * 48 + d];
        a = fmaxf(a, 0.0f);
        int j = lane / 40, tt = lane % 40;
        out[((k * TT + tt) * NN + n) * 2 + j] = a;
    } else if (lane == 80) {
        out[76800 + row] = score_acc[row] + 40.0f * scoreb[0];
    }
}

extern "C" void kernel_launch(void* const* d_in, const int* in_sizes, int n_in,
                              void* d_out, int out_size, void* d_ws, size_t ws_size,
                              hipStream_t stream) {
    const float* hx  = (const float*)d_in[0];
    const float* cur = (const float*)d_in[1];
    const float* yp  = (const float*)d_in[2];
    const float* img = (const float*)d_in[3];
    const float* c1w = (const float*)d_in[4];
    const float* c1b = (const float*)d_in[5];
    const float* c2w = (const float*)d_in[6];
    const float* c2b = (const float*)d_in[7];
    const float* vw  = (const float*)d_in[8];
    const float* vb  = (const float*)d_in[9];
    const float* wih = (const float*)d_in[10];
    const float* whh = (const float*)d_in[11];
    const float* bih = (const float*)d_in[12];
    const float* bhh = (const float*)d_in[13];
    const float* scfw = (const float*)d_in[14];
    const float* scfb = (const float*)d_in[15];
    const float* scw  = (const float*)d_in[16];
    const float* scb  = (const float*)d_in[17];
    const float* dyw  = (const float*)d_in[18];
    const float* dyb  = (const float*)d_in[19];
    float* out = (float*)d_out;

    char* ws = (char*)d_ws;
    float* fmap1      = (float*)(ws + 0);          // 409600
    float* fmap       = (float*)(ws + 409600);     // 819200
    u16*   lhalf_bf   = (u16*)(ws + 1228800);      // 3686400
    signed char* win  = (signed char*)(ws + 4915200);    // 1382400
    unsigned char* cnt = (unsigned char*)(ws + 6297600); // 1382400
    float* h0hist     = (float*)(ws + 7680000);    // 755712
    float* hfin       = (float*)(ws + 8435712);    // 184320
    float* score_acc  = (float*)(ws + 8620032);    // 3840
    u16*   wscf_t     = (u16*)(ws + 8623872);      // 221184
    u16*   wrz_g      = (u16*)(ws + 8845056);      // 30720
    u16*   win_g      = (u16*)(ws + 8875776);      // 9216
    u16*   whn_g      = (u16*)(ws + 8884992);      // 6144
    float* bias5      = (float*)(ws + 8891136);    // 960

    static int attr_done = 0;
    // hipFuncSetAttribute is idempotent and host-side; safe under graph capture.
    hipFuncSetAttribute((const void*)chain_k, hipFuncAttributeMaxDynamicSharedMemorySize,
                        SMEM_BYTES);
    hipFuncSetAttribute((const void*)foll_k, hipFuncAttributeMaxDynamicSharedMemorySize,
                        SMEM_BYTES);
    (void)attr_done;

    conv1_k<<<400, 256, 0, stream>>>(img, c1w, c1b, fmap1);
    conv2_k<<<800, 256, 0, stream>>>(fmap1, c2w, c2b, fmap);
    prep_w2<<<(110592 + 15360 + 4608 + 3072 + 240 + 255) / 256, 256, 0, stream>>>(
        scfw, wih, whh, bih, bhh, scfb, wscf_t, wrz_g, win_g, whn_g, bias5);
    lhalf_k<<<TT * KK * NN, 64, 0, stream>>>(yp, cur, fmap, vw, vb, lhalf_bf);
    bins2_k<<<TT * KK, 256, 0, stream>>>(yp, win, cnt);

    chain_k<<<1, 1024, SMEM_BYTES, stream>>>(hx, h0hist, lhalf_bf, win, cnt, wscf_t,
                                             wrz_g, win_g, whn_g, bias5, scw, score_acc, hfin);
    foll_k<<<9, 1024, SMEM_BYTES, stream>>>(hx, h0hist, lhalf_bf, win, cnt, wscf_t,
                                            wrz_g, win_g, whn_g, bias5, scw, score_acc, hfin);
    final_k<<<960, 128, 0, stream>>>(hfin, score_acc, dyw, dyb, scb, out);
}

// Round 5
// 922.657 us; speedup vs baseline: 2.9323x; 2.9323x over previous
//
#include <hip/hip_runtime.h>
#include <math.h>

#define KK 10
#define NN 96
#define TT 40

#define HZf 10.0f
#define R0f 0.5f
#define R1f 4.0f
#define RSTEPf ((4.0f - 0.5f) / 6.0f)
#define TWO_PIf 6.2831853071795864769f
#define TSTEPf (6.2831853071795864769f / 6.0f)

typedef unsigned short u16;
typedef unsigned int u32;

__device__ __forceinline__ u16 f2bf(float f) {
    union { float f; unsigned u; } v; v.f = f;
    unsigned r = v.u + 0x7fffu + ((v.u >> 16) & 1u);
    return (u16)(r >> 16);
}
__device__ __forceinline__ float bflo(u32 u) {
    union { unsigned u; float f; } v; v.u = u << 16; return v.f;
}
__device__ __forceinline__ float bfhi(u32 u) {
    union { unsigned u; float f; } v; v.u = u & 0xffff0000u; return v.f;
}
__device__ __forceinline__ float bf2f(u16 h) {
    union { unsigned u; float f; } v; v.u = ((unsigned)h) << 16; return v.f;
}
__device__ __forceinline__ float sigmoidf_(float x) { return 1.0f / (1.0f + expf(-x)); }

// ---------------- conv1: (4,160,160) -> relu -> (16,80,80), s2 p2 ----------------
__global__ void conv1_k(const float* __restrict__ img, const float* __restrict__ w,
                        const float* __restrict__ b, float* __restrict__ out) {
    int idx = blockIdx.x * blockDim.x + threadIdx.x;
    if (idx >= 16 * 80 * 80) return;
    int x = idx % 80, y = (idx / 80) % 80, o = idx / 6400;
    float acc = b[o];
    for (int c = 0; c < 4; c++)
        for (int ky = 0; ky < 5; ky++) {
            int iy = y * 2 + ky - 2;
            if (iy < 0 || iy >= 160) continue;
            for (int kx = 0; kx < 5; kx++) {
                int ix = x * 2 + kx - 2;
                if (ix < 0 || ix >= 160) continue;
                acc += img[(c * 160 + iy) * 160 + ix] * w[((o * 4 + c) * 5 + ky) * 5 + kx];
            }
        }
    out[idx] = fmaxf(acc, 0.0f);
}

// ---------------- conv2: (16,80,80) -> relu -> (32,80,80), s1 p2 ----------------
__global__ void conv2_k(const float* __restrict__ in, const float* __restrict__ w,
                        const float* __restrict__ b, float* __restrict__ out) {
    int idx = blockIdx.x * blockDim.x + threadIdx.x;
    if (idx >= 32 * 80 * 80) return;
    int x = idx % 80, y = (idx / 80) % 80, o = idx / 6400;
    float acc = b[o];
    for (int c = 0; c < 16; c++)
        for (int ky = 0; ky < 5; ky++) {
            int iy = y + ky - 2;
            if (iy < 0 || iy >= 80) continue;
            for (int kx = 0; kx < 5; kx++) {
                int ix = x + kx - 2;
                if (ix < 0 || ix >= 80) continue;
                acc += in[(c * 80 + iy) * 80 + ix] * w[((o * 16 + c) * 5 + ky) * 5 + kx];
            }
        }
    out[idx] = fmaxf(acc, 0.0f);
}

// ---------------- weight prep: bf16 pair-packed planes ----------------
// x-layout for gates: [lh(48) | rh(48) | h(48)]  (K=144)
// Wr_p[dp<72][48], Wz_p[dp<72][48]: pair {F(2dp,row), F(2dp+1,row)}, row=od (r), 48+od (z)
//   F(kk,row) = kk<96 ? wih[row*96+kk] : whh[row*48+kk-96]
// Win_p[dp<48][48]: row=96+od, kk=2dp<96 from wih
// Whn_p[dp<24][48]: row=96+od, kk=2dp<48 from whh
// wscf_p[b][dp<24][48]: pair {scf[o*1728+b*48+2dp], ...+2dp+1}
// bias5[5][48]: bR=bih+bhh, bZ, bIN=bih[96+], bHN=bhh[96+], bSF=scfb
__global__ void prep_w3(const float* __restrict__ scf, const float* __restrict__ wih,
                        const float* __restrict__ whh, const float* __restrict__ bih,
                        const float* __restrict__ bhh, const float* __restrict__ scfb,
                        u32* __restrict__ wscf_p, u32* __restrict__ Wr_p,
                        u32* __restrict__ Wz_p, u32* __restrict__ Win_p,
                        u32* __restrict__ Whn_p, float* __restrict__ bias5) {
    int idx = blockIdx.x * blockDim.x + threadIdx.x;
    if (idx < 41472) {
        int o = idx % 48, dp = (idx / 48) % 24, b = idx / 1152;
        float v0 = scf[o * 1728 + b * 48 + 2 * dp];
        float v1 = scf[o * 1728 + b * 48 + 2 * dp + 1];
        wscf_p[idx] = (u32)f2bf(v0) | ((u32)f2bf(v1) << 16);
    } else if (idx < 44928) {
        int j = idx - 41472, od = j % 48, dp = j / 48;
        int kk0 = 2 * dp, kk1 = 2 * dp + 1;
        float v0 = kk0 < 96 ? wih[od * 96 + kk0] : whh[od * 48 + kk0 - 96];
        float v1 = kk1 < 96 ? wih[od * 96 + kk1] : whh[od * 48 + kk1 - 96];
        Wr_p[j] = (u32)f2bf(v0) | ((u32)f2bf(v1) << 16);
    } else if (idx < 48384) {
        int j = idx - 44928, od = j % 48, dp = j / 48;
        int row = 48 + od, kk0 = 2 * dp, kk1 = 2 * dp + 1;
        float v0 = kk0 < 96 ? wih[row * 96 + kk0] : whh[row * 48 + kk0 - 96];
        float v1 = kk1 < 96 ? wih[row * 96 + kk1] : whh[row * 48 + kk1 - 96];
        Wz_p[j] = (u32)f2bf(v0) | ((u32)f2bf(v1) << 16);
    } else if (idx < 50688) {
        int j = idx - 48384, od = j % 48, dp = j / 48;
        int row = 96 + od;
        Win_p[j] = (u32)f2bf(wih[row * 96 + 2 * dp]) | ((u32)f2bf(wih[row * 96 + 2 * dp + 1]) << 16);
    } else if (idx < 51840) {
        int j = idx - 50688, od = j % 48, dp = j / 48;
        int row = 96 + od;
        Whn_p[j] = (u32)f2bf(whh[row * 48 + 2 * dp]) | ((u32)f2bf(whh[row * 48 + 2 * dp + 1]) << 16);
    } else if (idx < 52080) {
        int j = idx - 51840, od = j % 48, q = j / 48;
        float v;
        if (q == 0) v = bih[od] + bhh[od];
        else if (q == 1) v = bih[48 + od] + bhh[48 + od];
        else if (q == 2) v = bih[96 + od];
        else if (q == 3) v = bhh[96 + od];
        else v = scfb[od];
        bias5[j] = v;
    }
}

// ---------------- lhalf (bf16) ----------------
__global__ void lhalf_k(const float* __restrict__ yp, const float* __restrict__ cur,
                        const float* __restrict__ fmap, const float* __restrict__ vw,
                        const float* __restrict__ vb, u16* __restrict__ lhalf_bf) {
    int item = blockIdx.x;  // t*960 + k*96 + n
    int n = item % NN, k = (item / NN) % KK, t = item / (KK * NN);
    int lane = threadIdx.x;
    float lx = yp[((k * TT + t) * NN + n) * 2 + 0];
    float ly = yp[((k * TT + t) * NN + n) * 2 + 1];
    float px, py;
    if (t == 0) { px = cur[n * 2]; py = cur[n * 2 + 1]; }
    else { px = yp[((k * TT + t - 1) * NN + n) * 2]; py = yp[((k * TT + t - 1) * NN + n) * 2 + 1]; }
    float vx = (lx - px) * HZf, vy = (ly - py) * HZf;
    int ui = 40 - (int)ly;
    int vi = 40 - (int)lx;
    ui = min(max(ui, 0), 79);
    vi = min(max(vi, 0), 79);
    int row = k * NN + n;
    u16* dst = lhalf_bf + ((size_t)t * 960 + row) * 48;
    if (lane < 32) {
        dst[lane] = f2bf(fmap[(lane * 80 + ui) * 80 + vi]);
    } else if (lane < 48) {
        int f = lane - 32;
        float a = vb[f] + vx * vw[f * 2 + 0] + vy * vw[f * 2 + 1];
        dst[lane] = f2bf(fmaxf(a, 0.0f));
    }
}

// ---------------- bins + packed occupied list ----------------
// binpk[(t*960+r)*37]: [0]=ne, [1..ne] = (b<<16)|(w<<8)|c
__global__ __launch_bounds__(256) void bins3_k(const float* __restrict__ yp,
                                               u32* __restrict__ binpk) {
    int tk = blockIdx.x;  // t*10 + k
    int k = tk % KK, t = tk / KK;
    int tid = threadIdx.x;
    __shared__ float xs[96], ys[96];
    __shared__ int win_s[96 * 36];
    __shared__ int cnt_s[96 * 36];
    if (tid < 96) {
        xs[tid] = yp[((k * TT + t) * NN + tid) * 2 + 0];
        ys[tid] = yp[((k * TT + t) * NN + tid) * 2 + 1];
    }
    for (int i = tid; i < 96 * 36; i += 256) { win_s[i] = -1; cnt_s[i] = 0; }
    __syncthreads();
    for (int p = tid; p < 96 * 96; p += 256) {
        int i = p / 96, j = p % 96;
        if (i == j) continue;
        float dx = xs[j] - xs[i], dy = ys[j] - ys[i];
        float dist = sqrtf(dx * dx + dy * dy);
        if (dist < R0f || dist > R1f) continue;
        float dsafe = fmaxf(dist, 1e-10f);
        float cost = fminf(fmaxf(dx / dsafe, -1.0f), 1.0f);
        float ac = acosf(cost);
        float theta = (dy < 0.0f) ? (TWO_PIf - ac) : ac;
        int ub = (int)((dist - R0f) / RSTEPf); ub = min(max(ub, 0), 5);
        int vb = (int)(theta / TSTEPf);        vb = min(max(vb, 0), 5);
        int b = ub * 6 + vb;
        atomicAdd(&cnt_s[i * 36 + b], 1);
        atomicMax(&win_s[i * 36 + b], j);
    }
    __syncthreads();
    if (tid < 96) {
        u32 base = (u32)(t * 960 + k * 96 + tid) * 37u;
        int ne = 0;
        for (int b = 0; b < 36; ++b) {
            int w = win_s[tid * 36 + b];
            if (w >= 0) {
                binpk[base + 1 + ne] = ((u32)b << 16) | ((u32)w << 8) | (u32)cnt_s[tid * 36 + b];
                ne++;
            }
        }
        binpk[base] = (u32)ne;
    }
}

// ---------------- gil: lh-dependent gate parts for chain rows ----------------
// gil[(t*96+r)*144 + {0:r,48:z,96:in}+od] (bf16)
__global__ __launch_bounds__(64) void gil_k(const u16* __restrict__ lhalf_bf,
                                            const u32* __restrict__ Wr_p,
                                            const u32* __restrict__ Wz_p,
                                            const u32* __restrict__ Win_p,
                                            u16* __restrict__ gil) {
    int bid = blockIdx.x;  // t*96 + r
    int r = bid % 96, t = bid / 96;
    int lane = threadIdx.x;
    int lo = lane < 48 ? lane : 47;
    __shared__ float shlh[48];
    if (lane < 48) shlh[lane] = bf2f(lhalf_bf[((size_t)t * 960 + r) * 48 + lane]);
    __syncthreads();
    float aR = 0.f, aZ = 0.f, aI = 0.f;
#pragma unroll 8
    for (int dp = 0; dp < 24; ++dp) {
        float xlo = shlh[2 * dp], xhi = shlh[2 * dp + 1];
        u32 uR = Wr_p[dp * 48 + lo], uZ = Wz_p[dp * 48 + lo], uI = Win_p[dp * 48 + lo];
        aR += bflo(uR) * xlo + bfhi(uR) * xhi;
        aZ += bflo(uZ) * xlo + bfhi(uZ) * xhi;
        aI += bflo(uI) * xlo + bfhi(uI) * xhi;
    }
    if (lane < 48) {
        u16* g = gil + (size_t)bid * 144;
        g[lane] = f2bf(aR);
        g[48 + lane] = f2bf(aZ);
        g[96 + lane] = f2bf(aI);
    }
}

// ---------------- init h0 slab ----------------
__global__ void init_h(const float* __restrict__ hx, float* __restrict__ h0hist) {
    int idx = blockIdx.x * blockDim.x + threadIdx.x;
    if (idx < 4608) h0hist[idx] = hx[idx];
}

// ---------------- one chain step: 96 blocks x 64 lanes ----------------
__global__ __launch_bounds__(64) void chain_step_k(
    int t, float* __restrict__ h0hist, const u32* __restrict__ binpk,
    const u32* __restrict__ wscf_p, const u32* __restrict__ Wr_p,
    const u32* __restrict__ Wz_p, const u32* __restrict__ Win_p,
    const u32* __restrict__ Whn_p, const float* __restrict__ bias5,
    const u16* __restrict__ gil, const float* __restrict__ scw,
    float* __restrict__ score_acc, float* __restrict__ hfin) {
    const int r = blockIdx.x, lane = threadIdx.x;
    const int lo = lane < 48 ? lane : 47;
    __shared__ float shh[48], shrh[48];
    __shared__ float shw[36][48];
    const float* hcur = h0hist + (size_t)t * 4608;
    float hprev = hcur[r * 48 + lo];
    if (lane < 48) shh[lane] = hprev;
    u32 base = (u32)(t * 960 + r) * 37u;
    int ne = (int)binpk[base];
    for (int e = 0; e < ne; ++e) {
        u32 u = binpk[base + 1 + e];
        int w = (int)((u >> 8) & 0xff);
        if (lane < 48) shw[e][lane] = hcur[w * 48 + lane];
    }
    __syncthreads();
    // rhalf
    float accrh = 0.f;
    for (int e = 0; e < ne; ++e) {
        u32 u = binpk[base + 1 + e];
        int b = (int)(u >> 16);
        float cinv = 1.0f / (float)(u & 0xff);
        float a = 0.f;
#pragma unroll 8
        for (int dp = 0; dp < 24; ++dp) {
            u32 wp = wscf_p[(b * 24 + dp) * 48 + lo];
            a += bflo(wp) * shw[e][2 * dp] + bfhi(wp) * shw[e][2 * dp + 1];
        }
        accrh += a * cinv;
    }
    float rh = fmaxf(accrh + bias5[192 + lo], 0.f);
    if (lane < 48) shrh[lane] = rh;
    __syncthreads();
    // gates (lh parts precomputed in gil)
    const u16* g = gil + (size_t)(t * 96 + r) * 144;
    float aR = bf2f(g[lo]), aZ = bf2f(g[48 + lo]), aI = bf2f(g[96 + lo]), aH = 0.f;
#pragma unroll 8
    for (int dp = 24; dp < 48; ++dp) {
        float xlo = shrh[2 * dp - 48], xhi = shrh[2 * dp - 47];
        u32 uR = Wr_p[dp * 48 + lo], uZ = Wz_p[dp * 48 + lo], uI = Win_p[dp * 48 + lo];
        aR += bflo(uR) * xlo + bfhi(uR) * xhi;
        aZ += bflo(uZ) * xlo + bfhi(uZ) * xhi;
        aI += bflo(uI) * xlo + bfhi(uI) * xhi;
    }
#pragma unroll 8
    for (int dp = 48; dp < 72; ++dp) {
        float xlo = shh[2 * dp - 96], xhi = shh[2 * dp - 95];
        u32 uR = Wr_p[dp * 48 + lo], uZ = Wz_p[dp * 48 + lo], uH = Whn_p[(dp - 48) * 48 + lo];
        aR += bflo(uR) * xlo + bfhi(uR) * xhi;
        aZ += bflo(uZ) * xlo + bfhi(uZ) * xhi;
        aH += bflo(uH) * xlo + bfhi(uH) * xhi;
    }
    float rr = sigmoidf_(aR + bias5[lo]);
    float zz = sigmoidf_(aZ + bias5[48 + lo]);
    float ng = tanhf(aI + bias5[96 + lo] + rr * (aH + bias5[144 + lo]));
    float hn = (1.0f - zz) * ng + zz * hprev;
    if (lane < 48) {
        h0hist[(size_t)(t + 1) * 4608 + r * 48 + lane] = hn;
        if (t == TT - 1) hfin[r * 48 + lane] = hn;
    }
    float sv = (lane < 48) ? hn * scw[lane] : 0.f;
    for (int off = 32; off; off >>= 1) sv += __shfl_down(sv, off);
    if (lane == 0) score_acc[r] = (t == 0 ? 0.f : score_acc[r]) + sv;
}

// ---------------- followers: 864 blocks x 64 lanes, 40 steps internal ----------------
__global__ __launch_bounds__(64) void foll_k(
    const float* __restrict__ hx, const float* __restrict__ h0hist,
    const u16* __restrict__ lhalf_bf, const u32* __restrict__ binpk,
    const u32* __restrict__ wscf_p, const u32* __restrict__ Wr_p,
    const u32* __restrict__ Wz_p, const u32* __restrict__ Win_p,
    const u32* __restrict__ Whn_p, const float* __restrict__ bias5,
    const float* __restrict__ scw, float* __restrict__ score_acc,
    float* __restrict__ hfin) {
    const int r = 96 + blockIdx.x;
    const int lane = threadIdx.x;
    const int lo = lane < 48 ? lane : 47;
    __shared__ u32 sWr[3456], sWz[3456], sWhn[1152];
    __shared__ float shlh[48], shrh[48], shh[48];
    __shared__ float shw[12][48];
    for (int i = lane; i < 3456; i += 64) { sWr[i] = Wr_p[i]; sWz[i] = Wz_p[i]; }
    for (int i = lane; i < 1152; i += 64) sWhn[i] = Whn_p[i];
    float hreg = hx[(r % 96) * 48 + lo];
    const float bRb = bias5[lo], bZb = bias5[48 + lo], bIb = bias5[96 + lo],
                bHb = bias5[144 + lo], bSb = bias5[192 + lo];
    const float swv = (lane < 48) ? scw[lane] : 0.f;
    float score = 0.f;
    __syncthreads();
    for (int t = 0; t < TT; ++t) {
        const float* hcur = h0hist + (size_t)t * 4608;
        if (lane < 48) {
            shlh[lane] = bf2f(lhalf_bf[((size_t)t * 960 + r) * 48 + lane]);
            shh[lane] = hreg;
        }
        u32 base = (u32)(t * 960 + r) * 37u;
        int ne = (int)binpk[base];
        int npre = ne < 12 ? ne : 12;
        for (int e = 0; e < npre; ++e) {
            u32 u = binpk[base + 1 + e];
            int w = (int)((u >> 8) & 0xff);
            if (lane < 48) shw[e][lane] = hcur[w * 48 + lane];
        }
        __syncthreads();
        // rhalf
        float accrh = 0.f;
        for (int e = 0; e < ne; ++e) {
            u32 u = binpk[base + 1 + e];
            int b = (int)(u >> 16);
            float cinv = 1.0f / (float)(u & 0xff);
            int slot = e < 12 ? e : (e - 12) % 12;
            if (e >= 12) {
                if (lane < 48) shw[slot][lane] = hcur[((u >> 8) & 0xff) * 48 + lane];
                __syncthreads();
            }
            float a = 0.f;
#pragma unroll 8
            for (int dp = 0; dp < 24; ++dp) {
                u32 wp = wscf_p[(b * 24 + dp) * 48 + lo];
                a += bflo(wp) * shw[slot][2 * dp] + bfhi(wp) * shw[slot][2 * dp + 1];
            }
            accrh += a * cinv;
        }
        float rh = fmaxf(accrh + bSb, 0.f);
        if (lane < 48) shrh[lane] = rh;
        __syncthreads();
        // gates: full dots (lh, rh, h)
        float aR = 0.f, aZ = 0.f, aI = 0.f, aH = 0.f;
#pragma unroll 8
        for (int dp = 0; dp < 24; ++dp) {
            float xlo = shlh[2 * dp], xhi = shlh[2 * dp + 1];
            u32 uR = sWr[dp * 48 + lo], uZ = sWz[dp * 48 + lo], uI = Win_p[dp * 48 + lo];
            aR += bflo(uR) * xlo + bfhi(uR) * xhi;
            aZ += bflo(uZ) * xlo + bfhi(uZ) * xhi;
            aI += bflo(uI) * xlo + bfhi(uI) * xhi;
        }
#pragma unroll 8
        for (int dp = 24; dp < 48; ++dp) {
            float xlo = shrh[2 * dp - 48], xhi = shrh[2 * dp - 47];
            u32 uR = sWr[dp * 48 + lo], uZ = sWz[dp * 48 + lo], uI = Win_p[dp * 48 + lo];
            aR += bflo(uR) * xlo + bfhi(uR) * xhi;
            aZ += bflo(uZ) * xlo + bfhi(uZ) * xhi;
            aI += bflo(uI) * xlo + bfhi(uI) * xhi;
        }
#pragma unroll 8
        for (int dp = 48; dp < 72; ++dp) {
            float xlo = shh[2 * dp - 96], xhi = shh[2 * dp - 95];
            u32 uR = sWr[dp * 48 + lo], uZ = sWz[dp * 48 + lo], uH = sWhn[(dp - 48) * 48 + lo];
            aR += bflo(uR) * xlo + bfhi(uR) * xhi;
            aZ += bflo(uZ) * xlo + bfhi(uZ) * xhi;
            aH += bflo(uH) * xlo + bfhi(uH) * xhi;
        }
        float rr = sigmoidf_(aR + bRb);
        float zz = sigmoidf_(aZ + bZb);
        float ng = tanhf(aI + bIb + rr * (aH + bHb));
        hreg = (1.0f - zz) * ng + zz * hreg;
        score += hreg * swv;
        __syncthreads();
    }
    if (lane < 48) hfin[(size_t)r * 48 + lane] = hreg;
    for (int off = 32; off; off >>= 1) score += __shfl_down(score, off);
    if (lane == 0) score_acc[r] = score;
}

// ---------------- epilogue ----------------
__global__ void final_k(const float* __restrict__ hlast, const float* __restrict__ score_acc,
                        const float* __restrict__ dyw, const float* __restrict__ dyb,
                        const float* __restrict__ scoreb, float* __restrict__ out) {
    int row = blockIdx.x, lane = threadIdx.x;
    int n = row % 96, k = row / 96;
    __shared__ float sh_h[48];
    if (lane < 48) sh_h[lane] = hlast[row * 48 + lane];
    __syncthreads();
    if (lane < 80) {
        float a = dyb[lane];
#pragma unroll 8
        for (int d = 0; d < 48; d++) a += sh_h[d] * dyw[lane * 48 + d];
        a = fmaxf(a, 0.0f);
        int j = lane / 40, tt = lane % 40;
        out[((k * TT + tt) * NN + n) * 2 + j] = a;
    } else if (lane == 80) {
        out[76800 + row] = score_acc[row] + 40.0f * scoreb[0];
    }
}

extern "C" void kernel_launch(void* const* d_in, const int* in_sizes, int n_in,
                              void* d_out, int out_size, void* d_ws, size_t ws_size,
                              hipStream_t stream) {
    const float* hx  = (const float*)d_in[0];
    const float* cur = (const float*)d_in[1];
    const float* yp  = (const float*)d_in[2];
    const float* img = (const float*)d_in[3];
    const float* c1w = (const float*)d_in[4];
    const float* c1b = (const float*)d_in[5];
    const float* c2w = (const float*)d_in[6];
    const float* c2b = (const float*)d_in[7];
    const float* vw  = (const float*)d_in[8];
    const float* vb  = (const float*)d_in[9];
    const float* wih = (const float*)d_in[10];
    const float* whh = (const float*)d_in[11];
    const float* bih = (const float*)d_in[12];
    const float* bhh = (const float*)d_in[13];
    const float* scfw = (const float*)d_in[14];
    const float* scfb = (const float*)d_in[15];
    const float* scw  = (const float*)d_in[16];
    const float* scb  = (const float*)d_in[17];
    const float* dyw  = (const float*)d_in[18];
    const float* dyb  = (const float*)d_in[19];
    float* out = (float*)d_out;

    char* ws = (char*)d_ws;
    // [0, 409600)        fmap1 (dead after conv2); then gil (bf16, 1105920 B) after lhalf_k
    // [409600, 1228800)  fmap  (dead after lhalf_k)
    float* fmap1    = (float*)(ws + 0);
    u16*   gil      = (u16*)(ws + 0);               // 1105920 B, written by gil_k
    float* fmap     = (float*)(ws + 409600);
    u16*   lhalf_bf = (u16*)(ws + 1228800);         // 3686400 -> 4915200
    u32*   binpk    = (u32*)(ws + 4915200);         // 5683200 -> 10598400
    float* h0hist   = (float*)(ws + 10598400);      // 755712  -> 11354112
    float* hfin     = (float*)(ws + 11354112);      // 184320  -> 11538432
    float* score_acc= (float*)(ws + 11538432);      // 3840    -> 11542272
    u32*   wscf_p   = (u32*)(ws + 11542272);        // 165888  -> 11708160
    u32*   Wr_p     = (u32*)(ws + 11708160);        // 13824   -> 11721984
    u32*   Wz_p     = (u32*)(ws + 11721984);        // 13824   -> 11735808
    u32*   Win_p    = (u32*)(ws + 11735808);        // 9216    -> 11745024
    u32*   Whn_p    = (u32*)(ws + 11745024);        // 4608    -> 11749632
    float* bias5    = (float*)(ws + 11749632);      // 960     -> 11750592

    conv1_k<<<400, 256, 0, stream>>>(img, c1w, c1b, fmap1);
    conv2_k<<<800, 256, 0, stream>>>(fmap1, c2w, c2b, fmap);
    prep_w3<<<204, 256, 0, stream>>>(scfw, wih, whh, bih, bhh, scfb, wscf_p, Wr_p, Wz_p,
                                     Win_p, Whn_p, bias5);
    lhalf_k<<<TT * KK * NN, 64, 0, stream>>>(yp, cur, fmap, vw, vb, lhalf_bf);
    bins3_k<<<TT * KK, 256, 0, stream>>>(yp, binpk);
    gil_k<<<TT * 96, 64, 0, stream>>>(lhalf_bf, Wr_p, Wz_p, Win_p, gil);
    init_h<<<18, 256, 0, stream>>>(hx, h0hist);

    for (int t = 0; t < TT; ++t) {
        chain_step_k<<<96, 64, 0, stream>>>(t, h0hist, binpk, wscf_p, Wr_p, Wz_p, Win_p,
                                            Whn_p, bias5, gil, scw, score_acc, hfin);
    }
    foll_k<<<864, 64, 0, stream>>>(hx, h0hist, lhalf_bf, binpk, wscf_p, Wr_p, Wz_p, Win_p,
                                   Whn_p, bias5, scw, score_acc, hfin);
    final_k<<<960, 128, 0, stream>>>(hfin, score_acc, dyw, dyb, scb, out);
}

// Round 7
// 650.359 us; speedup vs baseline: 4.1601x; 1.4187x over previous
//
#include <hip/hip_runtime.h>
#include <math.h>

#define KK 10
#define NN 96
#define TT 40

#define HZf 10.0f
#define R0f 0.5f
#define R1f 4.0f
#define RSTEPf ((4.0f - 0.5f) / 6.0f)
#define TWO_PIf 6.2831853071795864769f
#define TSTEPf (6.2831853071795864769f / 6.0f)

typedef unsigned short u16;
typedef unsigned int u32;
typedef unsigned long long u64;

__device__ __forceinline__ u16 f2bf(float f) {
    union { float f; unsigned u; } v; v.f = f;
    unsigned r = v.u + 0x7fffu + ((v.u >> 16) & 1u);
    return (u16)(r >> 16);
}
__device__ __forceinline__ float bflo(u32 u) {
    union { unsigned u; float f; } v; v.u = u << 16; return v.f;
}
__device__ __forceinline__ float bfhi(u32 u) {
    union { unsigned u; float f; } v; v.u = u & 0xffff0000u; return v.f;
}
__device__ __forceinline__ float bf2f(u16 h) {
    union { unsigned u; float f; } v; v.u = ((unsigned)h) << 16; return v.f;
}
__device__ __forceinline__ float sigmoidf_(float x) { return 1.0f / (1.0f + expf(-x)); }

// ---------------- conv1: (4,160,160) -> relu -> (16,80,80), s2 p2 ----------------
__global__ void conv1_k(const float* __restrict__ img, const float* __restrict__ w,
                        const float* __restrict__ b, float* __restrict__ out) {
    int idx = blockIdx.x * blockDim.x + threadIdx.x;
    if (idx >= 16 * 80 * 80) return;
    int x = idx % 80, y = (idx / 80) % 80, o = idx / 6400;
    float acc = b[o];
    for (int c = 0; c < 4; c++)
        for (int ky = 0; ky < 5; ky++) {
            int iy = y * 2 + ky - 2;
            if (iy < 0 || iy >= 160) continue;
            for (int kx = 0; kx < 5; kx++) {
                int ix = x * 2 + kx - 2;
                if (ix < 0 || ix >= 160) continue;
                acc += img[(c * 160 + iy) * 160 + ix] * w[((o * 4 + c) * 5 + ky) * 5 + kx];
            }
        }
    out[idx] = fmaxf(acc, 0.0f);
}

// ---------------- conv2: (16,80,80) -> relu -> (32,80,80), s1 p2 ----------------
__global__ void conv2_k(const float* __restrict__ in, const float* __restrict__ w,
                        const float* __restrict__ b, float* __restrict__ out) {
    int idx = blockIdx.x * blockDim.x + threadIdx.x;
    if (idx >= 32 * 80 * 80) return;
    int x = idx % 80, y = (idx / 80) % 80, o = idx / 6400;
    float acc = b[o];
    for (int c = 0; c < 16; c++)
        for (int ky = 0; ky < 5; ky++) {
            int iy = y + ky - 2;
            if (iy < 0 || iy >= 80) continue;
            for (int kx = 0; kx < 5; kx++) {
                int ix = x + kx - 2;
                if (ix < 0 || ix >= 80) continue;
                acc += in[(c * 80 + iy) * 80 + ix] * w[((o * 16 + c) * 5 + ky) * 5 + kx];
            }
        }
    out[idx] = fmaxf(acc, 0.0f);
}

// ---------------- weight prep: bf16 pair-packed planes ----------------
// x-layout for gates: [lh(48) | rh(48) | h(48)]  (K=144)
__global__ void prep_w3(const float* __restrict__ scf, const float* __restrict__ wih,
                        const float* __restrict__ whh, const float* __restrict__ bih,
                        const float* __restrict__ bhh, const float* __restrict__ scfb,
                        u32* __restrict__ wscf_p, u32* __restrict__ Wr_p,
                        u32* __restrict__ Wz_p, u32* __restrict__ Win_p,
                        u32* __restrict__ Whn_p, float* __restrict__ bias5) {
    int idx = blockIdx.x * blockDim.x + threadIdx.x;
    if (idx < 41472) {
        int o = idx % 48, dp = (idx / 48) % 24, b = idx / 1152;
        float v0 = scf[o * 1728 + b * 48 + 2 * dp];
        float v1 = scf[o * 1728 + b * 48 + 2 * dp + 1];
        wscf_p[idx] = (u32)f2bf(v0) | ((u32)f2bf(v1) << 16);
    } else if (idx < 44928) {
        int j = idx - 41472, od = j % 48, dp = j / 48;
        int kk0 = 2 * dp, kk1 = 2 * dp + 1;
        float v0 = kk0 < 96 ? wih[od * 96 + kk0] : whh[od * 48 + kk0 - 96];
        float v1 = kk1 < 96 ? wih[od * 96 + kk1] : whh[od * 48 + kk1 - 96];
        Wr_p[j] = (u32)f2bf(v0) | ((u32)f2bf(v1) << 16);
    } else if (idx < 48384) {
        int j = idx - 44928, od = j % 48, dp = j / 48;
        int row = 48 + od, kk0 = 2 * dp, kk1 = 2 * dp + 1;
        float v0 = kk0 < 96 ? wih[row * 96 + kk0] : whh[row * 48 + kk0 - 96];
        float v1 = kk1 < 96 ? wih[row * 96 + kk1] : whh[row * 48 + kk1 - 96];
        Wz_p[j] = (u32)f2bf(v0) | ((u32)f2bf(v1) << 16);
    } else if (idx < 50688) {
        int j = idx - 48384, od = j % 48, dp = j / 48;
        int row = 96 + od;
        Win_p[j] = (u32)f2bf(wih[row * 96 + 2 * dp]) | ((u32)f2bf(wih[row * 96 + 2 * dp + 1]) << 16);
    } else if (idx < 51840) {
        int j = idx - 50688, od = j % 48, dp = j / 48;
        int row = 96 + od;
        Whn_p[j] = (u32)f2bf(whh[row * 48 + 2 * dp]) | ((u32)f2bf(whh[row * 48 + 2 * dp + 1]) << 16);
    } else if (idx < 52080) {
        int j = idx - 51840, od = j % 48, q = j / 48;
        float v;
        if (q == 0) v = bih[od] + bhh[od];
        else if (q == 1) v = bih[48 + od] + bhh[48 + od];
        else if (q == 2) v = bih[96 + od];
        else if (q == 3) v = bhh[96 + od];
        else v = scfb[od];
        bias5[j] = v;
    }
}

// ---------------- lhalf (bf16) ----------------
__global__ void lhalf_k(const float* __restrict__ yp, const float* __restrict__ cur,
                        const float* __restrict__ fmap, const float* __restrict__ vw,
                        const float* __restrict__ vb, u16* __restrict__ lhalf_bf) {
    int item = blockIdx.x;  // t*960 + k*96 + n
    int n = item % NN, k = (item / NN) % KK, t = item / (KK * NN);
    int lane = threadIdx.x;
    float lx = yp[((k * TT + t) * NN + n) * 2 + 0];
    float ly = yp[((k * TT + t) * NN + n) * 2 + 1];
    float px, py;
    if (t == 0) { px = cur[n * 2]; py = cur[n * 2 + 1]; }
    else { px = yp[((k * TT + t - 1) * NN + n) * 2]; py = yp[((k * TT + t - 1) * NN + n) * 2 + 1]; }
    float vx = (lx - px) * HZf, vy = (ly - py) * HZf;
    int ui = 40 - (int)ly;
    int vi = 40 - (int)lx;
    ui = min(max(ui, 0), 79);
    vi = min(max(vi, 0), 79);
    int row = k * NN + n;
    u16* dst = lhalf_bf + ((size_t)t * 960 + row) * 48;
    if (lane < 32) {
        dst[lane] = f2bf(fmap[(lane * 80 + ui) * 80 + vi]);
    } else if (lane < 48) {
        int f = lane - 32;
        float a = vb[f] + vx * vw[f * 2 + 0] + vy * vw[f * 2 + 1];
        dst[lane] = f2bf(fmaxf(a, 0.0f));
    }
}

// ---------------- bins: compact 80B/row-step: u64 mask + u16 entries (w<<8|c) ----------------
__global__ __launch_bounds__(256) void bins4_k(const float* __restrict__ yp,
                                               u32* __restrict__ binc) {
    int tk = blockIdx.x;  // t*10 + k
    int k = tk % KK, t = tk / KK;
    int tid = threadIdx.x;
    __shared__ float xs[96], ys[96];
    __shared__ int win_s[96 * 36];
    __shared__ int cnt_s[96 * 36];
    if (tid < 96) {
        xs[tid] = yp[((k * TT + t) * NN + tid) * 2 + 0];
        ys[tid] = yp[((k * TT + t) * NN + tid) * 2 + 1];
    }
    for (int i = tid; i < 96 * 36; i += 256) { win_s[i] = -1; cnt_s[i] = 0; }
    __syncthreads();
    for (int p = tid; p < 96 * 96; p += 256) {
        int i = p / 96, j = p % 96;
        if (i == j) continue;
        float dx = xs[j] - xs[i], dy = ys[j] - ys[i];
        float dist = sqrtf(dx * dx + dy * dy);
        if (dist < R0f || dist > R1f) continue;
        float dsafe = fmaxf(dist, 1e-10f);
        float cost = fminf(fmaxf(dx / dsafe, -1.0f), 1.0f);
        float ac = acosf(cost);
        float theta = (dy < 0.0f) ? (TWO_PIf - ac) : ac;
        int ub = (int)((dist - R0f) / RSTEPf); ub = min(max(ub, 0), 5);
        int vb = (int)(theta / TSTEPf);        vb = min(max(vb, 0), 5);
        int b = ub * 6 + vb;
        atomicAdd(&cnt_s[i * 36 + b], 1);
        atomicMax(&win_s[i * 36 + b], j);
    }
    __syncthreads();
    if (tid < 96) {
        u32 base = (u32)(t * 960 + k * 96 + tid) * 20u;
        u16* entg = (u16*)(binc + base + 2);
        u64 mask = 0ull;
        int ne = 0;
        for (int b = 0; b < 36; ++b) {
            int w = win_s[tid * 36 + b];
            if (w >= 0) {
                mask |= 1ull << b;
                entg[ne++] = (u16)((w << 8) | cnt_s[tid * 36 + b]);
            }
        }
        binc[base] = (u32)mask;
        binc[base + 1] = (u32)(mask >> 32);
    }
}

// ---------------- init h0 slab ----------------
__global__ void init_h(const float* __restrict__ hx, float* __restrict__ h0hist) {
    int idx = blockIdx.x * blockDim.x + threadIdx.x;
    if (idx < 4608) h0hist[idx] = hx[idx];
}

// ---------------- one chain step + rhalf_all piggyback ----------------
// blocks 0..95: chain row r (4 waves, K-split). blocks 96..311: rhalf for follower
// rows (4 waves, one row each), using h0hist[t] published by the previous launch.
__global__ __launch_bounds__(256) void step_k(
    int t, float* __restrict__ h0hist, const u16* __restrict__ lhalf_bf,
    const u32* __restrict__ binc, const u32* __restrict__ wscf_p,
    const u32* __restrict__ Wr_p, const u32* __restrict__ Wz_p,
    const u32* __restrict__ Win_p, const u32* __restrict__ Whn_p,
    const float* __restrict__ bias5, const float* __restrict__ scw,
    float* __restrict__ score_acc, float* __restrict__ hfin,
    u16* __restrict__ rhalf_all) {
    __shared__ float smf[6912];
    const float* hcur = h0hist + (size_t)t * 4608;
    const int tid = threadIdx.x;
    const int wv = tid >> 6, lane = tid & 63;
    const int lo = lane < 48 ? lane : 47;

    if (blockIdx.x < 96) {
        const int r = blockIdx.x;
        float* shw = smf;                    // 1728
        float* shx = smf + 1728;             // 144  [lh|rh|h]
        float* ps1 = smf + 1872;             // 192  [4][48]
        float* ps2 = smf + 2064;             // 768  [4][4][48]
        u32* sent = (u32*)(smf + 2832);      // 20
        unsigned char* blist = (unsigned char*)(smf + 2852);  // 36

        if (tid < 20) sent[tid] = binc[(size_t)(t * 960 + r) * 20 + tid];
        if (tid < 48) {
            shx[tid] = bf2f(lhalf_bf[((size_t)t * 960 + r) * 48 + tid]);
            shx[96 + tid] = hcur[r * 48 + tid];
        }
        __syncthreads();
        u64 mask = ((u64)sent[1] << 32) | sent[0];
        int ne = __popcll(mask);
        const u16* ent = (const u16*)(sent + 2);
        if (tid < 36 && ((mask >> tid) & 1)) {
            int rank = __popcll(mask & ((1ull << tid) - 1ull));
            blist[rank] = (unsigned char)tid;
        }
        for (int i = tid; i < ne * 48; i += 256) {
            int e = i / 48, c = i - e * 48;
            int w = (ent[e] >> 8) & 0xff;
            shw[i] = hcur[w * 48 + c];
        }
        __syncthreads();
        // phase1: rhalf, wave wv covers dp [6wv, 6wv+6)
        float acc = 0.f;
        for (int e = 0; e < ne; ++e) {
            int b = blist[e];
            float cinv = 1.0f / (float)(ent[e] & 0xff);
            const u32* wp = wscf_p + (b * 24 + wv * 6) * 48 + lo;
            const float* xv = shw + e * 48 + wv * 12;
            float a = 0.f;
#pragma unroll
            for (int dp = 0; dp < 6; ++dp) {
                u32 u = wp[dp * 48];
                a += bflo(u) * xv[2 * dp] + bfhi(u) * xv[2 * dp + 1];
            }
            acc += a * cinv;
        }
        if (lane < 48) ps1[wv * 48 + lane] = acc;
        __syncthreads();
        if (wv == 0 && lane < 48) {
            float rh = ps1[lane] + ps1[48 + lane] + ps1[96 + lane] + ps1[144 + lane] +
                       bias5[192 + lane];
            shx[48 + lane] = fmaxf(rh, 0.f);
        }
        __syncthreads();
        // phase2: gates, wave wv covers dp [18wv, 18wv+18)
        float aR = 0.f, aZ = 0.f, aI = 0.f, aH = 0.f;
        int dp0 = wv * 18;
#pragma unroll
        for (int i = 0; i < 18; ++i) {
            int dp = dp0 + i;
            u32 uR = Wr_p[dp * 48 + lo], uZ = Wz_p[dp * 48 + lo];
            float xlo = shx[2 * dp], xhi = shx[2 * dp + 1];
            aR += bflo(uR) * xlo + bfhi(uR) * xhi;
            aZ += bflo(uZ) * xlo + bfhi(uZ) * xhi;
            if (dp < 48) {
                u32 uI = Win_p[dp * 48 + lo];
                aI += bflo(uI) * xlo + bfhi(uI) * xhi;
            } else {
                u32 uH = Whn_p[(dp - 48) * 48 + lo];
                aH += bflo(uH) * xlo + bfhi(uH) * xhi;
            }
        }
        if (lane < 48) {
            ps2[(wv * 4 + 0) * 48 + lane] = aR;
            ps2[(wv * 4 + 1) * 48 + lane] = aZ;
            ps2[(wv * 4 + 2) * 48 + lane] = aI;
            ps2[(wv * 4 + 3) * 48 + lane] = aH;
        }
        __syncthreads();
        if (wv == 0) {
            float sv = 0.f;
            if (lane < 48) {
                float AR = 0.f, AZ = 0.f, AI = 0.f, AH = 0.f;
#pragma unroll
                for (int w2 = 0; w2 < 4; ++w2) {
                    AR += ps2[(w2 * 4 + 0) * 48 + lane];
                    AZ += ps2[(w2 * 4 + 1) * 48 + lane];
                    AI += ps2[(w2 * 4 + 2) * 48 + lane];
                    AH += ps2[(w2 * 4 + 3) * 48 + lane];
                }
                float hprev = shx[96 + lane];
                float rr = sigmoidf_(AR + bias5[lane]);
                float zz = sigmoidf_(AZ + bias5[48 + lane]);
                float ng = tanhf(AI + bias5[96 + lane] + rr * (AH + bias5[144 + lane]));
                float hn = (1.0f - zz) * ng + zz * hprev;
                h0hist[(size_t)(t + 1) * 4608 + r * 48 + lane] = hn;
                if (t == TT - 1) hfin[r * 48 + lane] = hn;
                sv = hn * scw[lane];
            }
            for (int off = 32; off; off >>= 1) sv += __shfl_down(sv, off);
            if (lane == 0) score_acc[r] = (t == 0 ? 0.f : score_acc[r]) + sv;
        }
    } else {
        // rhalf piggyback: wave = one follower row
        int widx = (blockIdx.x - 96) * 4 + wv;  // 0..863
        int row = 96 + widx;
        float* myw = smf + wv * 1728;
        const u32* bp = binc + (size_t)(t * 960 + row) * 20;
        u64 mask = ((u64)bp[1] << 32) | bp[0];
        int ne = __popcll(mask);
        const u16* ent = (const u16*)(bp + 2);
        for (int i = lane; i < ne * 48; i += 64) {
            int e = i / 48, c = i - e * 48;
            int w = (ent[e] >> 8) & 0xff;
            myw[i] = hcur[w * 48 + c];
        }
        __syncthreads();
        float acc = 0.f;
        u64 m2 = mask;
        for (int e = 0; e < ne; ++e) {
            int b = __ffsll((long long)m2) - 1;
            m2 &= m2 - 1;
            float cinv = 1.0f / (float)(ent[e] & 0xff);
            const u32* wp = wscf_p + b * 24 * 48 + lo;
            const float* xv = myw + e * 48;
            float a = 0.f;
#pragma unroll 8
            for (int dp = 0; dp < 24; ++dp) {
                u32 u = wp[dp * 48];
                a += bflo(u) * xv[2 * dp] + bfhi(u) * xv[2 * dp + 1];
            }
            acc += a * cinv;
        }
        float rh = fmaxf(acc + bias5[192 + lo], 0.f);
        if (lane < 48) rhalf_all[((size_t)t * 864 + widx) * 48 + lane] = f2bf(rh);
    }
}

// ---------------- followers: x-parts precomputed; weights LDS; h-part in regs/LDS ----------------
__global__ __launch_bounds__(64) void foll2_k(
    const float* __restrict__ hx, const u16* __restrict__ lhalf_bf,
    const u16* __restrict__ rhalf_all, const u32* __restrict__ Wr_p,
    const u32* __restrict__ Wz_p, const u32* __restrict__ Win_p,
    const u32* __restrict__ Whn_p, const float* __restrict__ bias5,
    const float* __restrict__ scw, float* __restrict__ score_acc,
    float* __restrict__ hfin) {
    const int widx = blockIdx.x;  // 0..863
    const int row = 96 + widx;
    const int lane = threadIdx.x;
    const int lo = lane < 48 ? lane : 47;
    __shared__ u32 sWr[3456], sWz[3456], sWin[2304];
    __shared__ u32 sx[48];
    __shared__ float shh[48];
    for (int i = lane; i < 3456; i += 64) { sWr[i] = Wr_p[i]; sWz[i] = Wz_p[i]; }
    for (int i = lane; i < 2304; i += 64) sWin[i] = Win_p[i];
    u32 whn[24];
#pragma unroll
    for (int dp = 0; dp < 24; ++dp) whn[dp] = Whn_p[dp * 48 + lo];
    float hreg = hx[(row % 96) * 48 + lo];
    const float bRb = bias5[lo], bZb = bias5[48 + lo], bIb = bias5[96 + lo],
                bHb = bias5[144 + lo];
    const float swv = (lane < 48) ? scw[lane] : 0.f;
    float score = 0.f;
    __syncthreads();
    for (int t = 0; t < TT; ++t) {
        if (lane < 24) {
            sx[lane] = *(const u32*)(lhalf_bf + ((size_t)t * 960 + row) * 48 + 2 * lane);
            sx[24 + lane] = *(const u32*)(rhalf_all + ((size_t)t * 864 + widx) * 48 + 2 * lane);
        }
        if (lane < 48) shh[lane] = hreg;
        __syncthreads();
        float aR = 0.f, aZ = 0.f, aI = 0.f, aH = 0.f;
#pragma unroll 8
        for (int dp = 0; dp < 48; ++dp) {
            u32 xp = sx[dp];
            float xlo = bflo(xp), xhi = bfhi(xp);
            u32 uR = sWr[dp * 48 + lo], uZ = sWz[dp * 48 + lo], uI = sWin[dp * 48 + lo];
            aR += bflo(uR) * xlo + bfhi(uR) * xhi;
            aZ += bflo(uZ) * xlo + bfhi(uZ) * xhi;
            aI += bflo(uI) * xlo + bfhi(uI) * xhi;
        }
#pragma unroll 8
        for (int dp = 48; dp < 72; ++dp) {
            float xlo = shh[2 * dp - 96], xhi = shh[2 * dp - 95];
            u32 uR = sWr[dp * 48 + lo], uZ = sWz[dp * 48 + lo], uH = whn[dp - 48];
            aR += bflo(uR) * xlo + bfhi(uR) * xhi;
            aZ += bflo(uZ) * xlo + bfhi(uZ) * xhi;
            aH += bflo(uH) * xlo + bfhi(uH) * xhi;
        }
        float rr = sigmoidf_(aR + bRb);
        float zz = sigmoidf_(aZ + bZb);
        float ng = tanhf(aI + bIb + rr * (aH + bHb));
        hreg = (1.0f - zz) * ng + zz * hreg;
        score += hreg * swv;
        __syncthreads();
    }
    if (lane < 48) hfin[(size_t)row * 48 + lane] = hreg;
    for (int off = 32; off; off >>= 1) score += __shfl_down(score, off);
    if (lane == 0) score_acc[row] = score;
}

// ---------------- epilogue ----------------
__global__ void final_k(const float* __restrict__ hlast, const float* __restrict__ score_acc,
                        const float* __restrict__ dyw, const float* __restrict__ dyb,
                        const float* __restrict__ scoreb, float* __restrict__ out) {
    int row = blockIdx.x, lane = threadIdx.x;
    int n = row % 96, k = row / 96;
    __shared__ float sh_h[48];
    if (lane < 48) sh_h[lane] = hlast[row * 48 + lane];
    __syncthreads();
    if (lane < 80) {
        float a = dyb[lane];
#pragma unroll 8
        for (int d = 0; d < 48; d++) a += sh_h[d] * dyw[lane * 48 + d];
        a = fmaxf(a, 0.0f);
        int j = lane / 40, tt = lane % 40;
        out[((k * TT + tt) * NN + n) * 2 + j] = a;
    } else if (lane == 80) {
        out[76800 + row] = score_acc[row] + 40.0f * scoreb[0];
    }
}

extern "C" void kernel_launch(void* const* d_in, const int* in_sizes, int n_in,
                              void* d_out, int out_size, void* d_ws, size_t ws_size,
                              hipStream_t stream) {
    const float* hx  = (const float*)d_in[0];
    const float* cur = (const float*)d_in[1];
    const float* yp  = (const float*)d_in[2];
    const float* img = (const float*)d_in[3];
    const float* c1w = (const float*)d_in[4];
    const float* c1b = (const float*)d_in[5];
    const float* c2w = (const float*)d_in[6];
    const float* c2b = (const float*)d_in[7];
    const float* vw  = (const float*)d_in[8];
    const float* vb  = (const float*)d_in[9];
    const float* wih = (const float*)d_in[10];
    const float* whh = (const float*)d_in[11];
    const float* bih = (const float*)d_in[12];
    const float* bhh = (const float*)d_in[13];
    const float* scfw = (const float*)d_in[14];
    const float* scfb = (const float*)d_in[15];
    const float* scw  = (const float*)d_in[16];
    const float* scb  = (const float*)d_in[17];
    const float* dyw  = (const float*)d_in[18];
    const float* dyb  = (const float*)d_in[19];
    float* out = (float*)d_out;

    char* ws = (char*)d_ws;
    // Layout (total 11,228,352 B). fmap1/fmap alias the front of binc: they are
    // dead after lhalf_k, and bins4_k (which writes binc) runs after lhalf_k.
    u32*   binc     = (u32*)(ws + 0);           // 3,072,000 -> 3072000
    float* fmap1    = (float*)(ws + 0);         //   409,600 (dead after conv2)
    float* fmap     = (float*)(ws + 409600);    //   819,200 (dead after lhalf_k)
    u16*   rhalf_all= (u16*)(ws + 3072000);     // 3,317,760 -> 6389760
    u16*   lhalf_bf = (u16*)(ws + 6389760);     // 3,686,400 -> 10076160
    float* h0hist   = (float*)(ws + 10076160);  //   755,712 -> 10831872
    float* hfin     = (float*)(ws + 10831872);  //   184,320 -> 11016192
    float* score_acc= (float*)(ws + 11016192);  //     3,840 -> 11020032
    u32*   wscf_p   = (u32*)(ws + 11020032);    //   165,888 -> 11185920
    u32*   Wr_p     = (u32*)(ws + 11185920);    //    13,824 -> 11199744
    u32*   Wz_p     = (u32*)(ws + 11199744);    //    13,824 -> 11213568
    u32*   Win_p    = (u32*)(ws + 11213568);    //     9,216 -> 11222784
    u32*   Whn_p    = (u32*)(ws + 11222784);    //     4,608 -> 11227392
    float* bias5    = (float*)(ws + 11227392);  //       960 -> 11228352

    conv1_k<<<400, 256, 0, stream>>>(img, c1w, c1b, fmap1);
    conv2_k<<<800, 256, 0, stream>>>(fmap1, c2w, c2b, fmap);
    prep_w3<<<204, 256, 0, stream>>>(scfw, wih, whh, bih, bhh, scfb, wscf_p, Wr_p, Wz_p,
                                     Win_p, Whn_p, bias5);
    lhalf_k<<<TT * KK * NN, 64, 0, stream>>>(yp, cur, fmap, vw, vb, lhalf_bf);
    bins4_k<<<TT * KK, 256, 0, stream>>>(yp, binc);
    init_h<<<18, 256, 0, stream>>>(hx, h0hist);

    for (int t = 0; t < TT; ++t) {
        step_k<<<312, 256, 0, stream>>>(t, h0hist, lhalf_bf, binc, wscf_p, Wr_p, Wz_p,
                                        Win_p, Whn_p, bias5, scw, score_acc, hfin,
                                        rhalf_all);
    }
    foll2_k<<<864, 64, 0, stream>>>(hx, lhalf_bf, rhalf_all, Wr_p, Wz_p, Win_p, Whn_p,
                                    bias5, scw, score_acc, hfin);
    final_k<<<960, 128, 0, stream>>>(hfin, score_acc, dyw, dyb, scb, out);
}